// Round 1
// baseline (123327.722 us; speedup 1.0000x reference)
//
#include <hip/hip_runtime.h>
#include <hip/hip_bf16.h>
#include <stdint.h>

#define NWG 256

typedef __attribute__((ext_vector_type(8))) short bf16x8;
typedef __attribute__((ext_vector_type(4))) float f32x4;

__device__ __forceinline__ short f2bf(float f) {
    unsigned u = __float_as_uint(f);
    unsigned r = (u + 0x7fffu + ((u >> 16) & 1u)) >> 16;
    return (short)r;
}

__device__ __forceinline__ void gload16(const void* g, void* l) {
    __builtin_amdgcn_global_load_lds(
        (const __attribute__((address_space(1))) void*)g,
        (__attribute__((address_space(3))) void*)l, 16, 0, 0);
}

// ---------------- P1: misc prep (grid-stride) ----------------
__global__ void prep_all(const int* __restrict__ x, const int* __restrict__ Vg, const int* __restrict__ Jg,
                         const float* __restrict__ emb, const float* __restrict__ embV, const float* __restrict__ embJ,
                         const float* __restrict__ Wih_e, const float* __restrict__ bih_e, const float* __restrict__ bhh_e,
                         const float* __restrict__ Wih_d, const float* __restrict__ Whh_d,
                         const float* __restrict__ bih_d, const float* __restrict__ bhh_d,
                         float* __restrict__ out,
                         short* __restrict__ Abf, short* __restrict__ Wbf,
                         float* __restrict__ benc, float* __restrict__ wsum, float* __restrict__ bdec,
                         float* __restrict__ hbufE, float* __restrict__ bufD, unsigned* __restrict__ bar)
{
    const size_t i0 = (size_t)blockIdx.x * blockDim.x + threadIdx.x;
    const size_t str = (size_t)gridDim.x * blockDim.x;
    // embedded gather -> out (3rd output) + bf16 copy for GEMM
    for (size_t i = i0; i < (size_t)4096 * 1024; i += str) {
        int t = (int)(i >> 10), j = (int)(i & 1023);
        float v = emb[(size_t)x[t] * 1024 + j];
        out[4195328 + i] = v;
        Abf[i] = f2bf(v);
    }
    for (size_t i = i0; i < (size_t)8192 * 1024; i += str) Wbf[i] = f2bf(Wih_e[i]);
    for (size_t i = i0; i < 8192; i += str) benc[i] = bih_e[i] + bhh_e[i];
    for (size_t i = i0; i < (size_t)4096 * 1024; i += str) wsum[i] = Wih_d[i] + Whh_d[i];
    for (size_t i = i0; i < 4096; i += str) bdec[i] = bih_d[i] + bhh_d[i];
    for (size_t i = i0; i < 1024; i += str) {
        out[1024 + i] = emb[1 * 1024 + i];                       // recon row 0 = emb[B_IDX]
        out[1024 + (size_t)4095 * 1024 + i] = emb[23 * 1024 + i]; // recon row 4095 = emb[X_IDX]
    }
    for (size_t i = i0; i < 128; i += str) {
        float v = embV[(size_t)Vg[0] * 128 + i];
        out[i] = v; bufD[i] = v;
        float u = embJ[(size_t)Jg[0] * 128 + i];
        out[896 + i] = u; bufD[896 + i] = u;
    }
    for (size_t i = i0; i < 2048; i += str) hbufE[i] = 0.f;
    if (i0 == 0) { bar[0] = 0u; bar[32] = 0u; }
}

// ---------------- P2: pg = W_ih_dec @ prev0 + b_dec ----------------
__global__ void prep_pg(const float* __restrict__ Wih_d, const float* __restrict__ emb,
                        const float* __restrict__ bih_d, const float* __restrict__ bhh_d,
                        float* __restrict__ pg)
{
    const int lane = threadIdx.x & 63, wv = threadIdx.x >> 6;
    const float* prev0 = emb + 23 * 1024;
    for (int rr = 0; rr < 16; rr++) {
        int row = blockIdx.x * 64 + wv * 16 + rr;
        float s = 0.f;
        #pragma unroll
        for (int q = 0; q < 16; q++) {
            int k = lane + q * 64;
            s += Wih_d[(size_t)row * 1024 + k] * prev0[k];
        }
        for (int o = 32; o; o >>= 1) s += __shfl_xor(s, o, 64);
        if (lane == 0) pg[row] = s + bih_d[row] + bhh_d[row];
    }
}

// ---------------- P3: Gx = embedded @ W_ih_enc^T + benc (bf16 MFMA) ----------------
__launch_bounds__(256, 2)
__global__ void gemm_xgates(const short* __restrict__ A,   // [4096][1024] bf16 bits
                            const short* __restrict__ B,   // [8192][1024] bf16 bits
                            const float* __restrict__ bias,// [8192]
                            float* __restrict__ C)         // [4096][8192]
{
    __shared__ short lA[128 * 32];
    __shared__ short lB[128 * 32];
    const int bid = blockIdx.x;
    const int mb = bid >> 6;        // 32 M-blocks
    const int nb = bid & 63;        // 64 N-blocks
    const int tid = threadIdx.x, lane = tid & 63, wv = tid >> 6;
    const int wr = wv >> 1, wc = wv & 1;
    const int Mbase = mb * 128, Nbase = nb * 128;
    f32x4 acc[4][4] = {};

    for (int kt = 0; kt < 32; kt++) {
        __syncthreads();
        const int k0b = kt * 64;    // byte offset within a 2048B row
        #pragma unroll
        for (int c = 0; c < 2; c++) {
            int f = tid * 16 + c * 4096;
            int row = f >> 6, kb = f & 63;
            const char* ga = (const char*)A + (size_t)(Mbase + row) * 2048 + k0b + kb;
            const char* gb = (const char*)B + (size_t)(Nbase + row) * 2048 + k0b + kb;
            gload16(ga, (char*)lA + wv * 1024 + c * 4096);
            gload16(gb, (char*)lB + wv * 1024 + c * 4096);
        }
        asm volatile("s_waitcnt vmcnt(0)" ::: "memory");
        __syncthreads();
        bf16x8 af[4], bf[4];
        #pragma unroll
        for (int i = 0; i < 4; i++) {
            af[i] = *(const bf16x8*)&lA[(wr * 64 + i * 16 + (lane & 15)) * 32 + (lane >> 4) * 8];
            bf[i] = *(const bf16x8*)&lB[(wc * 64 + i * 16 + (lane & 15)) * 32 + (lane >> 4) * 8];
        }
        #pragma unroll
        for (int i = 0; i < 4; i++)
            #pragma unroll
            for (int j = 0; j < 4; j++)
                acc[i][j] = __builtin_amdgcn_mfma_f32_16x16x32_bf16(af[i], bf[j], acc[i][j], 0, 0, 0);
    }
    #pragma unroll
    for (int i = 0; i < 4; i++) {
        #pragma unroll
        for (int j = 0; j < 4; j++) {
            int col = Nbase + wc * 64 + j * 16 + (lane & 15);
            float bv = bias[col];
            #pragma unroll
            for (int r = 0; r < 4; r++) {
                int row = Mbase + wr * 64 + i * 16 + (lane >> 4) * 4 + r;
                C[(size_t)row * 8192 + col] = acc[i][j][r] + bv;
            }
        }
    }
}

// ---------------- custom grid barrier (monotonic counter + release flag) ----------------
__device__ __forceinline__ void gbar(unsigned* bar, unsigned round) {
    unsigned target = (round + 1u) * NWG;
    unsigned old = __hip_atomic_fetch_add(&bar[0], 1u, __ATOMIC_ACQ_REL, __HIP_MEMORY_SCOPE_AGENT);
    if (old == target - 1u) {
        __hip_atomic_store(&bar[32], round + 1u, __ATOMIC_RELEASE, __HIP_MEMORY_SCOPE_AGENT);
    } else {
        while (__hip_atomic_load(&bar[32], __ATOMIC_ACQUIRE, __HIP_MEMORY_SCOPE_AGENT) < round + 1u) {
            __builtin_amdgcn_s_sleep(1);
        }
    }
}

// ---------------- P4: persistent sequential LSTM (cooperative) ----------------
__launch_bounds__(512, 2)
__global__ void rnn_seq(const float* __restrict__ Whh_e,   // [8192][2048]
                        const float* __restrict__ Wls,     // [768][2048]
                        const float* __restrict__ bls,     // [768]
                        const float* __restrict__ Whh_d,   // [4096][1024]
                        const float* __restrict__ Gx,      // [4096][8192]
                        const float* __restrict__ wsum,    // [4096][1024]
                        const float* __restrict__ bdec,    // [4096]
                        const float* __restrict__ pg,      // [4096]
                        float* __restrict__ hbufE,         // [2][2048]
                        float* __restrict__ bufD,          // [2][1024]
                        float* __restrict__ out,           // d_out
                        unsigned* __restrict__ bar)
{
    const int w = blockIdx.x;
    const int tid = threadIdx.x;
    const int lane = tid & 63, wv = tid >> 6;
    __shared__ float hl[2048];
    __shared__ float red[256];
    __shared__ float cst[8];

    // ---- encoder weights into VGPRs: 128 f32/thread ----
    const int rloc = lane & 31;
    const int khalf = lane >> 5;
    const int Renc = (rloc >> 3) * 2048 + 8 * w + (rloc & 7);
    const int kboff = wv * 256 + khalf * 128;
    float we[128];
    {
        const float* src = Whh_e + (size_t)Renc * 2048 + kboff;
        #pragma unroll
        for (int q = 0; q < 32; q++) {
            float4 v = *(const float4*)(src + 4 * q);
            we[4 * q] = v.x; we[4 * q + 1] = v.y; we[4 * q + 2] = v.z; we[4 * q + 3] = v.w;
        }
    }
    if (tid < 8) cst[tid] = 0.f;
    const int grow = (tid >> 3) * 2048 + 8 * w + (tid & 7);   // valid for tid<32

    unsigned round = 0;

    // ================= encoder: 4096 steps =================
    #pragma unroll 1
    for (int t = 0; t < 4096; t++) {
        float gxv = 0.f;
        if (tid < 32) gxv = Gx[(size_t)t * 8192 + grow];      // prefetch (x-part + bias)
        float4 hv = *(const float4*)(hbufE + (size_t)(t & 1) * 2048 + tid * 4);
        *(float4*)(hl + tid * 4) = hv;
        __syncthreads();

        float a0 = 0.f, a1 = 0.f, a2 = 0.f, a3 = 0.f;
        const float* hp = hl + kboff;
        #pragma unroll
        for (int q = 0; q < 32; q++) {
            float4 h4 = *(const float4*)(hp + 4 * q);
            a0 += we[4 * q] * h4.x; a1 += we[4 * q + 1] * h4.y;
            a2 += we[4 * q + 2] * h4.z; a3 += we[4 * q + 3] * h4.w;
        }
        float acc = (a0 + a1) + (a2 + a3);
        acc += __shfl_xor(acc, 32, 64);
        if (lane < 32) red[wv * 32 + lane] = acc;
        __syncthreads();

        if (tid < 32) {
            float g = 0.f;
            #pragma unroll
            for (int v = 0; v < 8; v++) g += red[v * 32 + tid];
            g += gxv;
            float gi = __shfl(g, (tid & 7), 64);
            float gf = __shfl(g, (tid & 7) + 8, 64);
            float gg = __shfl(g, (tid & 7) + 16, 64);
            float go = __shfl(g, (tid & 7) + 24, 64);
            if (tid < 8) {
                float c = cst[tid];
                float ig = 1.f / (1.f + expf(-gi));
                float fg = 1.f / (1.f + expf(-gf));
                float og = 1.f / (1.f + expf(-go));
                float cn = fg * c + ig * tanhf(gg);
                float hn = og * tanhf(cn);
                cst[tid] = cn;
                hbufE[(size_t)((t + 1) & 1) * 2048 + 8 * w + tid] = hn;
            }
            __threadfence();
            if (tid == 0) gbar(bar, round);
        }
        __syncthreads();
        round++;
    }

    // ================= latent: 3 rows per WG =================
    {
        if (wv < 3) {
            int row = 3 * w + wv;
            const float* wr = Wls + (size_t)row * 2048;
            const float* he = hbufE;   // h_enc in buffer 0
            float s = 0.f;
            #pragma unroll
            for (int q = 0; q < 32; q++) s += wr[lane + 64 * q] * he[lane + 64 * q];
            for (int o = 32; o; o >>= 1) s += __shfl_xor(s, o, 64);
            if (lane == 0) {
                float lv = tanhf(s + bls[row]);
                bufD[128 + row] = lv;
                out[128 + row] = lv;
            }
        }
        __syncthreads();
        if (tid == 0) { __threadfence(); gbar(bar, round); }
        __syncthreads();
        round++;
    }

    // ---- decoder weights into VGPRs: 32 f32/thread ----
    const int rd = lane & 15;
    const int Rdec = (rd >> 2) * 1024 + 4 * w + (rd & 3);
    const int kdoff = wv * 128 + (lane >> 4) * 32;
    float wd[32];
    {
        const float* src = wsum + (size_t)Rdec * 1024 + kdoff;
        #pragma unroll
        for (int q = 0; q < 8; q++) {
            float4 v = *(const float4*)(src + 4 * q);
            wd[4 * q] = v.x; wd[4 * q + 1] = v.y; wd[4 * q + 2] = v.z; wd[4 * q + 3] = v.w;
        }
    }
    float bdv = 0.f, pgv = 0.f;
    if (tid < 16) { bdv = bdec[Rdec]; pgv = pg[Rdec]; }
    if (tid < 4) cst[tid] = bufD[4 * w + tid];   // c0 = latent_cat slice

    // ================= decoder: 4094 steps =================
    #pragma unroll 1
    for (int s = 1; s <= 4094; s++) {
        if (tid < 256) {
            float4 hv = *(const float4*)(bufD + (size_t)((s - 1) & 1) * 1024 + tid * 4);
            *(float4*)(hl + tid * 4) = hv;
        }
        __syncthreads();

        float acc;
        if (s == 1) {
            const float* srcw = Whh_d + (size_t)Rdec * 1024 + kdoff;
            float a0 = 0.f, a1 = 0.f, a2 = 0.f, a3 = 0.f;
            #pragma unroll
            for (int q = 0; q < 8; q++) {
                float4 wv4 = *(const float4*)(srcw + 4 * q);
                float4 h4 = *(const float4*)(hl + kdoff + 4 * q);
                a0 += wv4.x * h4.x; a1 += wv4.y * h4.y;
                a2 += wv4.z * h4.z; a3 += wv4.w * h4.w;
            }
            acc = (a0 + a1) + (a2 + a3);
        } else {
            float a0 = 0.f, a1 = 0.f, a2 = 0.f, a3 = 0.f;
            #pragma unroll
            for (int q = 0; q < 8; q++) {
                float4 h4 = *(const float4*)(hl + kdoff + 4 * q);
                a0 += wd[4 * q] * h4.x; a1 += wd[4 * q + 1] * h4.y;
                a2 += wd[4 * q + 2] * h4.z; a3 += wd[4 * q + 3] * h4.w;
            }
            acc = (a0 + a1) + (a2 + a3);
        }
        acc += __shfl_xor(acc, 32, 64);
        acc += __shfl_xor(acc, 16, 64);
        if (lane < 16) red[wv * 16 + lane] = acc;
        __syncthreads();

        if (tid < 16) {
            float g = 0.f;
            #pragma unroll
            for (int v = 0; v < 8; v++) g += red[v * 16 + tid];
            g += (s == 1) ? pgv : bdv;
            float gi = __shfl(g, (tid & 3), 64);
            float gf = __shfl(g, (tid & 3) + 4, 64);
            float gg = __shfl(g, (tid & 3) + 8, 64);
            float go = __shfl(g, (tid & 3) + 12, 64);
            if (tid < 4) {
                float c = cst[tid];
                float ig = 1.f / (1.f + expf(-gi));
                float fg = 1.f / (1.f + expf(-gf));
                float og = 1.f / (1.f + expf(-go));
                float cn = fg * c + ig * tanhf(gg);
                float hn = og * tanhf(cn);
                cst[tid] = cn;
                bufD[(size_t)(s & 1) * 1024 + 4 * w + tid] = hn;
                out[1024 + (size_t)(4095 - s) * 1024 + 4 * w + tid] = hn;
            }
            __threadfence();
            if (tid == 0) gbar(bar, round);
        }
        __syncthreads();
        round++;
    }
}

// ---------------- host launcher ----------------
extern "C" void kernel_launch(void* const* d_in, const int* in_sizes, int n_in,
                              void* d_out, int out_size, void* d_ws, size_t ws_size,
                              hipStream_t stream)
{
    const int* x      = (const int*)d_in[0];
    const int* Vg     = (const int*)d_in[1];
    const int* Jg     = (const int*)d_in[2];
    // d_in[3] = tick (unused)
    const float* emb   = (const float*)d_in[4];
    const float* embV  = (const float*)d_in[5];
    const float* embJ  = (const float*)d_in[6];
    const float* Wih_e = (const float*)d_in[7];
    const float* Whh_e = (const float*)d_in[8];
    const float* bih_e = (const float*)d_in[9];
    const float* bhh_e = (const float*)d_in[10];
    const float* Wls   = (const float*)d_in[11];
    const float* bls   = (const float*)d_in[12];
    const float* Wih_d = (const float*)d_in[13];
    const float* Whh_d = (const float*)d_in[14];
    const float* bih_d = (const float*)d_in[15];
    const float* bhh_d = (const float*)d_in[16];
    float* out = (float*)d_out;

    char* ws = (char*)d_ws;
    float* wsf      = (float*)ws;
    unsigned* bar   = (unsigned*)ws;          // [0]=cnt, [32]=flag (separate lines)
    float* hbufE    = wsf + 64;               // [2][2048]
    float* bufD     = wsf + 4160;             // [2][1024]
    float* benc     = wsf + 6208;             // [8192]
    float* bdec     = wsf + 14400;            // [4096]
    float* pg       = wsf + 18496;            // [4096]
    short* Abf      = (short*)(ws + 90368);     // [4096*1024]
    short* Wbf      = (short*)(ws + 8478976);   // [8192*1024]
    float* wsum     = (float*)(ws + 25256192);  // [4096*1024]
    float* Gx       = (float*)(ws + 42033408);  // [4096*8192]
    // total ws needed: 176,251,136 bytes

    prep_all<<<1024, 256, 0, stream>>>(x, Vg, Jg, emb, embV, embJ,
                                       Wih_e, bih_e, bhh_e, Wih_d, Whh_d, bih_d, bhh_d,
                                       out, Abf, Wbf, benc, wsum, bdec, hbufE, bufD, bar);
    prep_pg<<<64, 256, 0, stream>>>(Wih_d, emb, bih_d, bhh_d, pg);
    gemm_xgates<<<2048, 256, 0, stream>>>(Abf, Wbf, benc, Gx);

    void* args[] = { (void*)&Whh_e, (void*)&Wls, (void*)&bls, (void*)&Whh_d,
                     (void*)&Gx, (void*)&wsum, (void*)&bdec, (void*)&pg,
                     (void*)&hbufE, (void*)&bufD, (void*)&out, (void*)&bar };
    hipLaunchCooperativeKernel((const void*)rnn_seq, dim3(NWG), dim3(512), args, 0, stream);
}

// Round 2
// 20931.746 us; speedup vs baseline: 5.8919x; 5.8919x over previous
//
#include <hip/hip_runtime.h>
#include <hip/hip_bf16.h>
#include <stdint.h>

#define NWG 256
typedef unsigned long long u64;

typedef __attribute__((ext_vector_type(8))) short bf16x8;
typedef __attribute__((ext_vector_type(4))) float f32x4;

__device__ __forceinline__ short f2bf(float f) {
    unsigned u = __float_as_uint(f);
    unsigned r = (u + 0x7fffu + ((u >> 16) & 1u)) >> 16;
    return (short)r;
}

__device__ __forceinline__ void gload16(const void* g, void* l) {
    __builtin_amdgcn_global_load_lds(
        (const __attribute__((address_space(1))) void*)g,
        (__attribute__((address_space(3))) void*)l, 16, 0, 0);
}

__device__ __forceinline__ u64 ald(const u64* p) {
    return __hip_atomic_load(p, __ATOMIC_RELAXED, __HIP_MEMORY_SCOPE_AGENT);
}
__device__ __forceinline__ void ast(u64* p, u64 v) {
    __hip_atomic_store(p, v, __ATOMIC_RELAXED, __HIP_MEMORY_SCOPE_AGENT);
}
__device__ __forceinline__ u64 pack(unsigned tag, float f) {
    return ((u64)tag << 32) | (u64)(unsigned)__float_as_uint(f);
}

// ---------------- P1: misc prep (grid-stride) ----------------
__global__ void prep_all(const int* __restrict__ x, const int* __restrict__ Vg, const int* __restrict__ Jg,
                         const float* __restrict__ emb, const float* __restrict__ embV, const float* __restrict__ embJ,
                         const float* __restrict__ Wih_e,
                         const float* __restrict__ Wih_d, const float* __restrict__ Whh_d,
                         float* __restrict__ out,
                         short* __restrict__ Abf, short* __restrict__ Wbf,
                         float* __restrict__ wsum,
                         u64* __restrict__ bufE, u64* __restrict__ bufD)
{
    const size_t i0 = (size_t)blockIdx.x * blockDim.x + threadIdx.x;
    const size_t str = (size_t)gridDim.x * blockDim.x;
    for (size_t i = i0; i < (size_t)4096 * 1024; i += str) {
        int t = (int)(i >> 10), j = (int)(i & 1023);
        float v = emb[(size_t)x[t] * 1024 + j];
        out[4195328 + i] = v;
        Abf[i] = f2bf(v);
    }
    for (size_t i = i0; i < (size_t)8192 * 1024; i += str) Wbf[i] = f2bf(Wih_e[i]);
    for (size_t i = i0; i < (size_t)4096 * 1024; i += str) wsum[i] = Wih_d[i] + Whh_d[i];
    for (size_t i = i0; i < 1024; i += str) {
        out[1024 + i] = emb[1 * 1024 + i];                        // recon row 0    = emb[B_IDX]
        out[1024 + (size_t)4095 * 1024 + i] = emb[23 * 1024 + i]; // recon row 4095 = emb[X_IDX]
    }
    // h-exchange buffers: encoder [3][2048] zeros (h_0 = 0, tag 0)
    for (size_t i = i0; i < 6144; i += str) bufE[i] = 0ull;
    // decoder [3][1024]: buf0 = latent_cat slots; buf1/2 zeros
    for (size_t i = i0; i < 3072; i += str) {
        u64 v = 0ull;
        if (i < 1024) {
            if (i < 128)      v = pack(0u, embV[(size_t)Vg[0] * 128 + i]);
            else if (i < 896) v = 0xFFFFFFFF00000000ull;   // latent sentinel
            else              v = pack(0u, embJ[(size_t)Jg[0] * 128 + (i - 896)]);
        }
        bufD[i] = v;
    }
    for (size_t i = i0; i < 128; i += str) {
        out[i]       = embV[(size_t)Vg[0] * 128 + i];
        out[896 + i] = embJ[(size_t)Jg[0] * 128 + i];
    }
}

// ---------------- P2: pg = W_ih_dec @ prev0 + b_dec ----------------
__global__ void prep_pg(const float* __restrict__ Wih_d, const float* __restrict__ emb,
                        const float* __restrict__ bih_d, const float* __restrict__ bhh_d,
                        float* __restrict__ pg)
{
    const int lane = threadIdx.x & 63, wv = threadIdx.x >> 6;
    const float* prev0 = emb + 23 * 1024;
    for (int rr = 0; rr < 16; rr++) {
        int row = blockIdx.x * 64 + wv * 16 + rr;
        float s = 0.f;
        #pragma unroll
        for (int q = 0; q < 16; q++) {
            int k = lane + q * 64;
            s += Wih_d[(size_t)row * 1024 + k] * prev0[k];
        }
        for (int o = 32; o; o >>= 1) s += __shfl_xor(s, o, 64);
        if (lane == 0) pg[row] = s + bih_d[row] + bhh_d[row];
    }
}

// ---------------- P3: Gx = embedded @ W_ih_enc^T + (bih+bhh) (bf16 MFMA) ----------------
__launch_bounds__(256, 2)
__global__ void gemm_xgates(const short* __restrict__ A,   // [4096][1024] bf16 bits
                            const short* __restrict__ B,   // [8192][1024] bf16 bits
                            const float* __restrict__ bih, const float* __restrict__ bhh,
                            float* __restrict__ C)         // [4096][8192]
{
    __shared__ short lA[128 * 32];
    __shared__ short lB[128 * 32];
    const int bid = blockIdx.x;
    const int mb = bid >> 6;
    const int nb = bid & 63;
    const int tid = threadIdx.x, lane = tid & 63, wv = tid >> 6;
    const int wr = wv >> 1, wc = wv & 1;
    const int Mbase = mb * 128, Nbase = nb * 128;
    f32x4 acc[4][4] = {};

    for (int kt = 0; kt < 32; kt++) {
        __syncthreads();
        const int k0b = kt * 64;
        #pragma unroll
        for (int c = 0; c < 2; c++) {
            int f = tid * 16 + c * 4096;
            int row = f >> 6, kb = f & 63;
            const char* ga = (const char*)A + (size_t)(Mbase + row) * 2048 + k0b + kb;
            const char* gb = (const char*)B + (size_t)(Nbase + row) * 2048 + k0b + kb;
            gload16(ga, (char*)lA + wv * 1024 + c * 4096);
            gload16(gb, (char*)lB + wv * 1024 + c * 4096);
        }
        asm volatile("s_waitcnt vmcnt(0)" ::: "memory");
        __syncthreads();
        bf16x8 af[4], bf[4];
        #pragma unroll
        for (int i = 0; i < 4; i++) {
            af[i] = *(const bf16x8*)&lA[(wr * 64 + i * 16 + (lane & 15)) * 32 + (lane >> 4) * 8];
            bf[i] = *(const bf16x8*)&lB[(wc * 64 + i * 16 + (lane & 15)) * 32 + (lane >> 4) * 8];
        }
        #pragma unroll
        for (int i = 0; i < 4; i++)
            #pragma unroll
            for (int j = 0; j < 4; j++)
                acc[i][j] = __builtin_amdgcn_mfma_f32_16x16x32_bf16(af[i], bf[j], acc[i][j], 0, 0, 0);
    }
    #pragma unroll
    for (int i = 0; i < 4; i++) {
        #pragma unroll
        for (int j = 0; j < 4; j++) {
            int col = Nbase + wc * 64 + j * 16 + (lane & 15);
            float bv = bih[col] + bhh[col];
            #pragma unroll
            for (int r = 0; r < 4; r++) {
                int row = Mbase + wr * 64 + i * 16 + (lane >> 4) * 4 + r;
                C[(size_t)row * 8192 + col] = acc[i][j][r] + bv;
            }
        }
    }
}

// ---------------- P4: persistent sequential LSTM (fence-free, value-tagged sync) ----------------
__launch_bounds__(512, 2)
__global__ void rnn_seq(const float* __restrict__ Whh_e,   // [8192][2048]
                        const float* __restrict__ Wls,     // [768][2048]
                        const float* __restrict__ bls,     // [768]
                        const float* __restrict__ Whh_d,   // [4096][1024]
                        const float* __restrict__ Gx,      // [4096][8192]
                        const float* __restrict__ wsum,    // [4096][1024]
                        const float* __restrict__ bih_d, const float* __restrict__ bhh_d,
                        const float* __restrict__ pg,      // [4096]
                        u64* __restrict__ bufE,            // [3][2048] tagged h (enc)
                        u64* __restrict__ bufD,            // [3][1024] tagged h (dec)
                        float* __restrict__ out)
{
    const int w = blockIdx.x;
    const int tid = threadIdx.x;
    const int lane = tid & 63, wv = tid >> 6;
    __shared__ float hl[2048];
    __shared__ float red[32];
    __shared__ float cst[8];

    // ---- encoder weights into VGPRs: wave wv owns row-slots [wv*4, wv*4+4),
    //      lane owns k = lane + 64*j  (strided; coalesced loads, conflict-free LDS reads)
    float we[128];
    #pragma unroll
    for (int rr = 0; rr < 4; rr++) {
        int ridx = wv * 4 + rr;
        const float* src = Whh_e + (size_t)((ridx >> 3) * 2048 + 8 * w + (ridx & 7)) * 2048 + lane;
        #pragma unroll
        for (int j = 0; j < 32; j++) we[rr * 32 + j] = src[64 * j];
    }
    if (tid < 8) cst[tid] = 0.f;
    const int grow = (tid >> 3) * 2048 + 8 * w + (tid & 7);   // valid for tid<32
    __syncthreads();

    // ================= encoder: 4096 steps =================
    #pragma unroll 1
    for (int t = 0; t < 4096; t++) {
        float gxv = 0.f;
        if (tid < 32) gxv = Gx[(size_t)t * 8192 + grow];      // prefetch x-gates (+bias)

        // poll own wave chunk of tagged h_t
        const unsigned tg = (unsigned)t;
        const u64* src = bufE + (size_t)(t % 3) * 2048 + wv * 256 + lane;
        u64 v0, v1, v2, v3;
        for (;;) {
            v0 = ald(src); v1 = ald(src + 64); v2 = ald(src + 128); v3 = ald(src + 192);
            bool ok = ((unsigned)(v0 >> 32) == tg) & ((unsigned)(v1 >> 32) == tg)
                    & ((unsigned)(v2 >> 32) == tg) & ((unsigned)(v3 >> 32) == tg);
            if (__all(ok)) break;
        }
        int b = wv * 256 + lane;
        hl[b]       = __uint_as_float((unsigned)v0);
        hl[b + 64]  = __uint_as_float((unsigned)v1);
        hl[b + 128] = __uint_as_float((unsigned)v2);
        hl[b + 192] = __uint_as_float((unsigned)v3);
        __syncthreads();

        float a0 = 0.f, a1 = 0.f, a2 = 0.f, a3 = 0.f;
        #pragma unroll
        for (int j = 0; j < 32; j++) {
            float hv = hl[lane + 64 * j];
            a0 += we[j] * hv; a1 += we[32 + j] * hv;
            a2 += we[64 + j] * hv; a3 += we[96 + j] * hv;
        }
        #pragma unroll
        for (int o = 32; o; o >>= 1) {
            a0 += __shfl_xor(a0, o, 64); a1 += __shfl_xor(a1, o, 64);
            a2 += __shfl_xor(a2, o, 64); a3 += __shfl_xor(a3, o, 64);
        }
        if (lane == 0) {
            red[wv * 4]     = a0; red[wv * 4 + 1] = a1;
            red[wv * 4 + 2] = a2; red[wv * 4 + 3] = a3;
        }
        __syncthreads();

        if (tid < 32) {
            float g = red[tid] + gxv;
            float gi = __shfl(g, (tid & 7), 64);
            float gf = __shfl(g, (tid & 7) + 8, 64);
            float gg = __shfl(g, (tid & 7) + 16, 64);
            float go = __shfl(g, (tid & 7) + 24, 64);
            if (tid < 8) {
                float c  = cst[tid];
                float ig = 1.f / (1.f + expf(-gi));
                float fg = 1.f / (1.f + expf(-gf));
                float og = 1.f / (1.f + expf(-go));
                float cn = fg * c + ig * tanhf(gg);
                float hn = og * tanhf(cn);
                cst[tid] = cn;
                ast(&bufE[(size_t)((t + 1) % 3) * 2048 + 8 * w + tid], pack((unsigned)(t + 1), hn));
            }
        }
        __syncthreads();
    }

    // ================= latent: 3 rows per WG (reads h_4096, tag 4096, in bufE[1]) =================
    {
        const unsigned tg = 4096u;
        const u64* src = bufE + (size_t)2048 + wv * 256 + lane;
        u64 v0, v1, v2, v3;
        for (;;) {
            v0 = ald(src); v1 = ald(src + 64); v2 = ald(src + 128); v3 = ald(src + 192);
            bool ok = ((unsigned)(v0 >> 32) == tg) & ((unsigned)(v1 >> 32) == tg)
                    & ((unsigned)(v2 >> 32) == tg) & ((unsigned)(v3 >> 32) == tg);
            if (__all(ok)) break;
        }
        int b = wv * 256 + lane;
        hl[b]       = __uint_as_float((unsigned)v0);
        hl[b + 64]  = __uint_as_float((unsigned)v1);
        hl[b + 128] = __uint_as_float((unsigned)v2);
        hl[b + 192] = __uint_as_float((unsigned)v3);
        __syncthreads();

        if (wv < 3) {
            int row = 3 * w + wv;
            const float* wr = Wls + (size_t)row * 2048 + lane;
            float s = 0.f;
            #pragma unroll
            for (int q = 0; q < 32; q++) s += wr[64 * q] * hl[lane + 64 * q];
            for (int o = 32; o; o >>= 1) s += __shfl_xor(s, o, 64);
            if (lane == 0) {
                float lv = tanhf(s + bls[row]);
                out[128 + row] = lv;
                ast(&bufD[128 + row], pack(0u, lv));
            }
        }
        __syncthreads();   // protect hl before decoder staging
    }

    // ---- decoder weights into VGPRs: wave wv owns row-slots [wv*2, wv*2+2), lane owns k = lane+64j
    float wd[32];
    #pragma unroll
    for (int rr = 0; rr < 2; rr++) {
        int ridx = wv * 2 + rr;
        const float* src = wsum + (size_t)((ridx >> 2) * 1024 + 4 * w + (ridx & 3)) * 1024 + lane;
        #pragma unroll
        for (int j = 0; j < 16; j++) wd[rr * 16 + j] = src[64 * j];
    }
    float bdv = 0.f, pgv = 0.f;
    if (tid < 16) {
        int R = (tid >> 2) * 1024 + 4 * w + (tid & 3);
        bdv = bih_d[R] + bhh_d[R];
        pgv = pg[R];
    }
    if (tid < 4) {   // c0 = latent_cat slice (poll tag 0)
        const u64* p = bufD + 4 * w + tid;
        u64 v;
        do { v = ald(p); } while ((unsigned)(v >> 32) != 0u);
        cst[tid] = __uint_as_float((unsigned)v);
    }
    __syncthreads();

    // ================= decoder: 4094 steps =================
    #pragma unroll 1
    for (int s = 1; s <= 4094; s++) {
        const unsigned tg = (unsigned)(s - 1);
        const u64* src = bufD + (size_t)((s - 1) % 3) * 1024 + wv * 128 + lane;
        u64 v0, v1;
        for (;;) {
            v0 = ald(src); v1 = ald(src + 64);
            bool ok = ((unsigned)(v0 >> 32) == tg) & ((unsigned)(v1 >> 32) == tg);
            if (__all(ok)) break;
        }
        hl[wv * 128 + lane]      = __uint_as_float((unsigned)v0);
        hl[wv * 128 + lane + 64] = __uint_as_float((unsigned)v1);
        __syncthreads();

        float a0 = 0.f, a1 = 0.f;
        if (s == 1) {
            #pragma unroll
            for (int rr = 0; rr < 2; rr++) {
                int ridx = wv * 2 + rr;
                const float* srcw = Whh_d + (size_t)((ridx >> 2) * 1024 + 4 * w + (ridx & 3)) * 1024 + lane;
                float a = 0.f;
                #pragma unroll
                for (int j = 0; j < 16; j++) a += srcw[64 * j] * hl[lane + 64 * j];
                if (rr) a1 = a; else a0 = a;
            }
        } else {
            #pragma unroll
            for (int j = 0; j < 16; j++) {
                float hv = hl[lane + 64 * j];
                a0 += wd[j] * hv; a1 += wd[16 + j] * hv;
            }
        }
        #pragma unroll
        for (int o = 32; o; o >>= 1) {
            a0 += __shfl_xor(a0, o, 64); a1 += __shfl_xor(a1, o, 64);
        }
        if (lane == 0) { red[wv * 2] = a0; red[wv * 2 + 1] = a1; }
        __syncthreads();

        if (tid < 16) {
            float g = red[tid] + ((s == 1) ? pgv : bdv);
            float gi = __shfl(g, (tid & 3), 64);
            float gf = __shfl(g, (tid & 3) + 4, 64);
            float gg = __shfl(g, (tid & 3) + 8, 64);
            float go = __shfl(g, (tid & 3) + 12, 64);
            if (tid < 4) {
                float c  = cst[tid];
                float ig = 1.f / (1.f + expf(-gi));
                float fg = 1.f / (1.f + expf(-gf));
                float og = 1.f / (1.f + expf(-go));
                float cn = fg * c + ig * tanhf(gg);
                float hn = og * tanhf(cn);
                cst[tid] = cn;
                out[1024 + (size_t)(4095 - s) * 1024 + 4 * w + tid] = hn;
                ast(&bufD[(size_t)(s % 3) * 1024 + 4 * w + tid], pack((unsigned)s, hn));
            }
        }
        __syncthreads();
    }
}

// ---------------- host launcher ----------------
extern "C" void kernel_launch(void* const* d_in, const int* in_sizes, int n_in,
                              void* d_out, int out_size, void* d_ws, size_t ws_size,
                              hipStream_t stream)
{
    const int* x      = (const int*)d_in[0];
    const int* Vg     = (const int*)d_in[1];
    const int* Jg     = (const int*)d_in[2];
    const float* emb   = (const float*)d_in[4];
    const float* embV  = (const float*)d_in[5];
    const float* embJ  = (const float*)d_in[6];
    const float* Wih_e = (const float*)d_in[7];
    const float* Whh_e = (const float*)d_in[8];
    const float* bih_e = (const float*)d_in[9];
    const float* bhh_e = (const float*)d_in[10];
    const float* Wls   = (const float*)d_in[11];
    const float* bls   = (const float*)d_in[12];
    const float* Wih_d = (const float*)d_in[13];
    const float* Whh_d = (const float*)d_in[14];
    const float* bih_d = (const float*)d_in[15];
    const float* bhh_d = (const float*)d_in[16];
    float* out = (float*)d_out;

    char* ws = (char*)d_ws;
    u64*   bufE = (u64*)ws;                     // [3][2048]  -> 49152 B
    u64*   bufD = (u64*)(ws + 49152);           // [3][1024]  -> 24576 B
    float* pg   = (float*)(ws + 73728);         // [4096]     -> 16384 B (ends 90112)
    short* Abf  = (short*)(ws + 90368);         // [4096*1024]
    short* Wbf  = (short*)(ws + 8478976);       // [8192*1024]
    float* wsum = (float*)(ws + 25256192);      // [4096*1024]
    float* Gx   = (float*)(ws + 42033408);      // [4096*8192]  (total 176,251,136 B)

    prep_all<<<1024, 256, 0, stream>>>(x, Vg, Jg, emb, embV, embJ,
                                       Wih_e, Wih_d, Whh_d,
                                       out, Abf, Wbf, wsum, bufE, bufD);
    prep_pg<<<64, 256, 0, stream>>>(Wih_d, emb, bih_d, bhh_d, pg);
    gemm_xgates<<<2048, 256, 0, stream>>>(Abf, Wbf, bih_e, bhh_e, Gx);

    void* args[] = { (void*)&Whh_e, (void*)&Wls, (void*)&bls, (void*)&Whh_d,
                     (void*)&Gx, (void*)&wsum, (void*)&bih_d, (void*)&bhh_d, (void*)&pg,
                     (void*)&bufE, (void*)&bufD, (void*)&out };
    hipLaunchCooperativeKernel((const void*)rnn_seq, dim3(NWG), dim3(512), args, 0, stream);
}